// Round 5
// baseline (138.949 us; speedup 1.0000x reference)
//
#include <hip/hip_runtime.h>
#include <math.h>

// TopKMoEGate: T = 16384, D = 1024, E = 64, topK = 2.
// Round 10: "fat block" wave-split-K, zero K-loop barriers, zero duplication.
//  - R5..R9 all land 63-85 us with every pipe <25%: the shared structure was
//    duplicated A loads/convs (2-4x), B image re-read 98-393 MB through L2,
//    and a barrier/near-use load every ~500cy exposing latency 16+ times.
//  - This round: 256 blocks (1/CU) x 4 waves; wave wv owns K-quarter
//    [wv*256, wv*256+256) for ALL 64 tokens x ALL 64 experts.
//      acc: 32 x f4 (128 VGPR); B: 12 x s8 frags straight from L2 image;
//      A read exactly once (67 MB total), converted exactly once.
//    NO __syncthreads in the K loop -- waves fully independent.
//  - Cross-wave K-reduce via Lsum[4][64][68] LDS (69.6 KB, 2-way aliasing
//    = free), ONE barrier, then r3-verified butterfly top-2 + softmax.
//  - __launch_bounds__(256,1): VGPR slack up to 512 (expect ~215, no spill).
//    Even if a CU gets 2 blocks: LDS 2x69.6<160 KB, VGPR 2x215<512 -> fits.

#define DDIM 1024
#define NEXP 64
#define NTOK 16384

typedef float f4 __attribute__((ext_vector_type(4)));
typedef short s8 __attribute__((ext_vector_type(8)));
typedef unsigned int u32;

static __device__ __forceinline__ void split3(float f, short& h, short& m, short& l) {
    const u32 uf = __float_as_uint(f);
    h = (short)(uf >> 16);
    const float r1 = f - __uint_as_float(uf & 0xffff0000u);
    const u32 u1 = __float_as_uint(r1);
    m = (short)(u1 >> 16);
    const float r2 = r1 - __uint_as_float(u1 & 0xffff0000u);
    l = (short)(__float_as_uint(r2) >> 16);
}

// ---- kernel 0: slice gate_w into 3 bf16 levels, lane-ordered image ----
// unit16 U'(c,kk,lv,t,q,m) = c*1536 + (kk*3+lv)*256 + t*64 + q*16 + m,
// holding w[e=t*16+m][k0..k0+7], k0 = c*64 + kk*32 + q*8.
__global__ __launch_bounds__(256)
void w_prep(const float* __restrict__ gw, short* __restrict__ wimg) {
    const int uid = blockIdx.x * 256 + threadIdx.x;   // 8192 threads
    const int c   = uid >> 9;
    const int kk  = (uid >> 8) & 1;
    const int e   = (uid >> 2) & 63;
    const int q   = uid & 3;
    const int k0  = c * 64 + kk * 32 + q * 8;
    const float* src = gw + (size_t)e * DDIM + k0;
    s8 hv, mv, lv;
    #pragma unroll
    for (int j = 0; j < 8; ++j) {
        short h, m, l;
        split3(src[j], h, m, l);
        hv[j] = h; mv[j] = m; lv[j] = l;
    }
    const size_t base = (size_t)c * 1536 + (kk * 3) * 256
                      + (e >> 4) * 64 + q * 16 + (e & 15);
    *(s8*)(wimg + (base      ) * 8) = hv;
    *(s8*)(wimg + (base + 256) * 8) = mv;
    *(s8*)(wimg + (base + 512) * 8) = lv;
}

// pack hi 16 bits of (flo, fhi) -> u32 {lo16 = hi(flo), hi16 = hi(fhi)}
static __device__ __forceinline__ u32 packhi(float flo, float fhi) {
    return __builtin_amdgcn_perm(__float_as_uint(fhi), __float_as_uint(flo),
                                 0x07060302u);
}

union FragU { u32 u[4]; s8 v; };

// convert 8 consecutive floats -> 3-level bf16 frags (h, m, l)  [r8-verified]
static __device__ __forceinline__ void conv8(const float* f, s8& h, s8& m, s8& l) {
    FragU H, M, L;
    #pragma unroll
    for (int j = 0; j < 4; ++j) {
        const float f0 = f[2 * j], f1 = f[2 * j + 1];
        H.u[j] = packhi(f0, f1);
        const float g0 = f0 - __uint_as_float(__float_as_uint(f0) & 0xffff0000u);
        const float g1 = f1 - __uint_as_float(__float_as_uint(f1) & 0xffff0000u);
        M.u[j] = packhi(g0, g1);
        const float e0 = g0 - __uint_as_float(__float_as_uint(g0) & 0xffff0000u);
        const float e1 = g1 - __uint_as_float(__float_as_uint(g1) & 0xffff0000u);
        L.u[j] = packhi(e0, e1);
    }
    h = H.v; m = M.v; l = L.v;
}

#define MF(A, B, C) __builtin_amdgcn_mfma_f32_16x16x32_bf16((A), (B), (C), 0, 0, 0)

// ---- kernel 1: fused GEMM + cross-wave reduce + noisy top-2 + softmax ----
__global__ __launch_bounds__(256, 1)
void gate_fused(const float* __restrict__ x,
                const short* __restrict__ wimg,
                const float* __restrict__ noise_weight,
                const float* __restrict__ noise,
                float* __restrict__ out_w,
                float* __restrict__ out_i)
{
    __shared__ float Lsum[4][64][68];           // [wave][token][expert], padded

    const int tid  = threadIdx.x;
    const int lane = tid & 63;
    const int wv   = tid >> 6;                  // K-quarter owner
    const int m    = lane & 15;
    const int q    = lane >> 4;
    const int tokBase = blockIdx.x * 64;

    // acc[mt][t]: token tile mt (16 tokens), expert tile t (16 experts)
    f4 a0[4][4], a1[4][4];
    #pragma unroll
    for (int mt = 0; mt < 4; ++mt)
        #pragma unroll
        for (int t = 0; t < 4; ++t) { a0[mt][t] = (f4)0.f; a1[mt][t] = (f4)0.f; }

    // wave's K range: chunks wv*4 .. wv*4+3 (k = wv*256 .. wv*256+255)
    const short* wbase = wimg + (size_t)(wv * 4) * 12288;       // shorts
    const float* xbase = x + (size_t)(tokBase + m) * DDIM + wv * 256 + q * 8;

    #pragma unroll
    for (int j = 0; j < 4; ++j) {
        #pragma unroll
        for (int kk = 0; kk < 2; ++kk) {
            // B fragments for this (chunk, kk): 12 x 1KB coalesced L2 loads
            const short* bp = wbase + (size_t)j * 12288 + kk * 3 * 2048;
            s8 B[12];
            #pragma unroll
            for (int t = 0; t < 4; ++t)
                #pragma unroll
                for (int lv = 0; lv < 3; ++lv)
                    B[t * 3 + lv] = *(const s8*)(bp + ((size_t)lv * 256 + t * 64 + lane) * 8);

            #pragma unroll
            for (int mt = 0; mt < 4; ++mt) {
                const float* ap = xbase + (size_t)mt * 16 * DDIM + j * 64 + kk * 32;
                const f4 x0 = *(const f4*)(ap);
                const f4 x1 = *(const f4*)(ap + 4);
                float xf[8];
                #pragma unroll
                for (int i = 0; i < 4; ++i) { xf[i] = x0[i]; xf[4 + i] = x1[i]; }
                s8 ah, am_, al;
                conv8(xf, ah, am_, al);
                #pragma unroll
                for (int t = 0; t < 4; ++t) {
                    const s8 bh = B[t * 3], bm = B[t * 3 + 1], bl = B[t * 3 + 2];
                    a0[mt][t] = MF(ah,  bh, a0[mt][t]);
                    a1[mt][t] = MF(ah,  bm, a1[mt][t]);
                    a1[mt][t] = MF(am_, bh, a1[mt][t]);
                    a1[mt][t] = MF(ah,  bl, a1[mt][t]);
                    a1[mt][t] = MF(am_, bm, a1[mt][t]);
                    a1[mt][t] = MF(al,  bh, a1[mt][t]);
                }
            }
        }
    }

    // write this wave's K-partial copy (C layout verified: lane(q,m), reg r
    // -> token mt*16+q*4+r, expert t*16+m). 2-way bank aliasing = free.
    #pragma unroll
    for (int mt = 0; mt < 4; ++mt)
        #pragma unroll
        for (int t = 0; t < 4; ++t)
            #pragma unroll
            for (int r = 0; r < 4; ++r)
                Lsum[wv][mt * 16 + q * 4 + r][t * 16 + m] = a0[mt][t][r] + a1[mt][t][r];

    // epilogue operands: issue before the barrier (acc regs now dead)
    const float nw = noise_weight[lane];
    float nz[16];
    #pragma unroll
    for (int tt = 0; tt < 16; ++tt)
        nz[tt] = noise[(size_t)(tokBase + wv * 16 + tt) * NEXP + lane];

    __syncthreads();

    // wave wv handles tokens wv*16 .. wv*16+15; lane = expert (r3-verified)
    #pragma unroll
    for (int tt = 0; tt < 16; ++tt) {
        const int tok  = wv * 16 + tt;
        const int gtok = tokBase + tok;
        const float ln = fmaf(nz[tt], nw,
                              (Lsum[0][tok][lane] + Lsum[1][tok][lane]) +
                              (Lsum[2][tok][lane] + Lsum[3][tok][lane]));

        float v1 = ln; int i1 = lane;
        #pragma unroll
        for (int off = 32; off > 0; off >>= 1) {
            const float vo = __shfl_xor(v1, off, 64);
            const int   io = __shfl_xor(i1, off, 64);
            if (vo > v1 || (vo == v1 && io < i1)) { v1 = vo; i1 = io; }
        }
        float v2 = (lane == i1) ? -3.4e38f : ln; int i2 = lane;
        #pragma unroll
        for (int off = 32; off > 0; off >>= 1) {
            const float vo = __shfl_xor(v2, off, 64);
            const int   io = __shfl_xor(i2, off, 64);
            if (vo > v2 || (vo == v2 && io < i2)) { v2 = vo; i2 = io; }
        }

        const float d   = expf(v2 - v1);
        const float inv = 1.f / (1.f + d);
        const float wgt = (lane == i1) ? inv : ((lane == i2) ? d * inv : 0.f);
        out_w[(size_t)gtok * NEXP + lane] = wgt;
        if (lane == 0) {
            out_i[(size_t)gtok * 2]     = (float)i1;
            out_i[(size_t)gtok * 2 + 1] = (float)i2;
        }
    }
}

extern "C" void kernel_launch(void* const* d_in, const int* in_sizes, int n_in,
                              void* d_out, int out_size, void* d_ws, size_t ws_size,
                              hipStream_t stream) {
    const float* x     = (const float*)d_in[0];
    const float* gw    = (const float*)d_in[1];
    const float* nwt   = (const float*)d_in[2];
    const float* noise = (const float*)d_in[3];
    float* out_w = (float*)d_out;                        // [NTOK][64]
    float* out_i = (float*)d_out + (size_t)NTOK * NEXP;  // [NTOK][2] as float

    short* wimg = (short*)d_ws;                          // 384 KB image

    hipLaunchKernelGGL(w_prep, dim3(32), dim3(256), 0, stream, gw, wimg);
    hipLaunchKernelGGL(gate_fused, dim3(NTOK / 64), dim3(256), 0, stream,
                       x, wimg, nwt, noise, out_w, out_i);
}

// Round 6
// 125.819 us; speedup vs baseline: 1.1044x; 1.1044x over previous
//
#include <hip/hip_runtime.h>
#include <math.h>

// TopKMoEGate: T = 16384, D = 1024, E = 64, topK = 2.
// Round 11: deep-queue DMA for BOTH x and B; concurrency-starvation fix.
//  - R5-R10 all 57-85 us with pipes <13% busy: Little's-law starvation.
//    Sync VGPR loads get re-sunk by the compiler (R7/R8 proved) and
//    serialize through few registers next to a fat accumulator (R10:
//    128/152 VGPR in acc). Fix: global_load_lds (deep fire-and-forget
//    queue, zero VGPR) for x too, issued a full chunk ahead; acc shrunk
//    to 32 VGPR via (expert-half, k-half) wave split.
//  - 512 blocks x 4 waves, block = 32 tok, full E, full K, 16 k64 chunks,
//    ONE __syncthreads per chunk. In-flight ~8KB/wave x 8 waves/CU.
//  - x LDS layout quad-swizzled (qd = sq ^ (tok&15), 16B granules keep
//    DMA contiguity): ds_read_b128 readback ~2-way = free. B image
//    stride-1 (free). conv dup 2x only. Epilogue fused; Lsum overlays
//    dead B buffer. LDS 64 KB -> 2 blocks/CU.

#define DDIM 1024
#define NEXP 64
#define NTOK 16384

typedef float f4 __attribute__((ext_vector_type(4)));
typedef short s8 __attribute__((ext_vector_type(8)));
typedef unsigned int u32;

static __device__ __forceinline__ void split3(float f, short& h, short& m, short& l) {
    const u32 uf = __float_as_uint(f);
    h = (short)(uf >> 16);
    const float r1 = f - __uint_as_float(uf & 0xffff0000u);
    const u32 u1 = __float_as_uint(r1);
    m = (short)(u1 >> 16);
    const float r2 = r1 - __uint_as_float(u1 & 0xffff0000u);
    l = (short)(__float_as_uint(r2) >> 16);
}

static __device__ __forceinline__ void gl_lds16(const void* g, void* l) {
    __builtin_amdgcn_global_load_lds(
        (const __attribute__((address_space(1))) u32*)g,
        (__attribute__((address_space(3))) u32*)l, 16, 0, 0);
}

// ---- kernel 0: slice gate_w into 3 bf16 levels, lane-ordered image ----
// unit16 U'(c,kk,lv,t,q,m) = c*1536 + (kk*3+lv)*256 + t*64 + q*16 + m,
// holding w[e=t*16+m][k0..k0+7], k0 = c*64 + kk*32 + q*8.  24 KB per chunk.
__global__ __launch_bounds__(256)
void w_prep(const float* __restrict__ gw, short* __restrict__ wimg) {
    const int uid = blockIdx.x * 256 + threadIdx.x;   // 8192 threads
    const int c   = uid >> 9;
    const int kk  = (uid >> 8) & 1;
    const int e   = (uid >> 2) & 63;
    const int q   = uid & 3;
    const int k0  = c * 64 + kk * 32 + q * 8;
    const float* src = gw + (size_t)e * DDIM + k0;
    s8 hv, mv, lv;
    #pragma unroll
    for (int j = 0; j < 8; ++j) {
        short h, m, l;
        split3(src[j], h, m, l);
        hv[j] = h; mv[j] = m; lv[j] = l;
    }
    const size_t base = (size_t)c * 1536 + (kk * 3) * 256
                      + (e >> 4) * 64 + q * 16 + (e & 15);
    *(s8*)(wimg + (base      ) * 8) = hv;
    *(s8*)(wimg + (base + 256) * 8) = mv;
    *(s8*)(wimg + (base + 512) * 8) = lv;
}

// pack hi 16 bits of (flo, fhi) -> u32 {lo16 = hi(flo), hi16 = hi(fhi)}
static __device__ __forceinline__ u32 packhi(float flo, float fhi) {
    return __builtin_amdgcn_perm(__float_as_uint(fhi), __float_as_uint(flo),
                                 0x07060302u);
}

union FragU { u32 u[4]; s8 v; };

// convert 8 consecutive floats -> 3-level bf16 frags (h, m, l)  [r8-verified]
static __device__ __forceinline__ void conv8(const float* f, s8& h, s8& m, s8& l) {
    FragU H, M, L;
    #pragma unroll
    for (int j = 0; j < 4; ++j) {
        const float f0 = f[2 * j], f1 = f[2 * j + 1];
        H.u[j] = packhi(f0, f1);
        const float g0 = f0 - __uint_as_float(__float_as_uint(f0) & 0xffff0000u);
        const float g1 = f1 - __uint_as_float(__float_as_uint(f1) & 0xffff0000u);
        M.u[j] = packhi(g0, g1);
        const float e0 = g0 - __uint_as_float(__float_as_uint(g0) & 0xffff0000u);
        const float e1 = g1 - __uint_as_float(__float_as_uint(g1) & 0xffff0000u);
        L.u[j] = packhi(e0, e1);
    }
    h = H.v; m = M.v; l = L.v;
}

#define MF(A, B, C) __builtin_amdgcn_mfma_f32_16x16x32_bf16((A), (B), (C), 0, 0, 0)

// ---- kernel 1: fused GEMM + noisy top-2 + sparse softmax ----
__global__ __launch_bounds__(256, 2)
void gate_fused(const float* __restrict__ x,
                const short* __restrict__ wimg,
                const float* __restrict__ noise_weight,
                const float* __restrict__ noise,
                float* __restrict__ out_w,
                float* __restrict__ out_i)
{
    __shared__ short bs[2][1536 * 8];           // 2 x 24 KB B chunk buffers
    __shared__ float xs[2][32 * 64];            // 2 x 8 KB x chunk (swizzled)

    const int tid  = threadIdx.x;
    const int lane = tid & 63;
    const int wv   = tid >> 6;
    const int es   = wv & 1;                    // expert half (2 t-tiles)
    const int kh   = wv >> 1;                   // k32 half of each chunk
    const int m    = lane & 15;
    const int q    = lane >> 4;
    const int tokBase = blockIdx.x * 32;

    // epilogue operands: issue now, retire under the K loop
    const float nw = noise_weight[lane];
    float nz[8];
    #pragma unroll
    for (int tt = 0; tt < 8; ++tt)
        nz[tt] = noise[(size_t)(tokBase + wv * 8 + tt) * NEXP + lane];

    f4 acc0[2][2], acc1[2][2];                  // [mt][tt]
    #pragma unroll
    for (int a = 0; a < 2; ++a)
        #pragma unroll
        for (int b = 0; b < 2; ++b) { acc0[a][b] = (f4)0.f; acc1[a][b] = (f4)0.f; }

    // stage chunk C into buffer BUF: B 24 KB linear, x 8 KB quad-swizzled src
#define STAGE(BUF, C) {                                                    \
    const short* _c = wimg + (size_t)(C) * 12288;                          \
    _Pragma("unroll")                                                      \
    for (int _i = 0; _i < 6; ++_i) {                                       \
        const int _off = (wv * 6 + _i) * 512;                              \
        gl_lds16(_c + _off + lane * 8, &bs[BUF][_off]);                    \
    }                                                                      \
    _Pragma("unroll")                                                      \
    for (int _j = 0; _j < 2; ++_j) {                                       \
        const int _qi = (wv * 2 + _j) * 64 + lane;                         \
        const int _tk = _qi >> 4;                                          \
        const int _qd = (_qi & 15) ^ (_tk & 15);                           \
        gl_lds16(x + (size_t)(tokBase + _tk) * DDIM + (C) * 64 + _qd * 4,  \
                 &xs[BUF][(wv * 2 + _j) * 256]);                           \
    } }

    // consume buffer BUF: wave (es, kh) does 2 mt x 2 tt x 6 MFMA
#define COMPUTE(BUF) {                                                     \
    s8 ah[2], am_[2], al[2];                                               \
    _Pragma("unroll")                                                      \
    for (int mt = 0; mt < 2; ++mt) {                                       \
        const int tok = mt * 16 + m;                                       \
        const int qd0 = kh * 8 + q * 2;                                    \
        const int sq0 = qd0 ^ (tok & 15);                                  \
        const int sq1 = (qd0 + 1) ^ (tok & 15);                            \
        const f4 xa = *(const f4*)&xs[BUF][tok * 64 + sq0 * 4];            \
        const f4 xb = *(const f4*)&xs[BUF][tok * 64 + sq1 * 4];            \
        float xf[8];                                                       \
        _Pragma("unroll")                                                  \
        for (int i = 0; i < 4; ++i) { xf[i] = xa[i]; xf[4 + i] = xb[i]; }  \
        conv8(xf, ah[mt], am_[mt], al[mt]);                                \
    }                                                                      \
    _Pragma("unroll")                                                      \
    for (int tt = 0; tt < 2; ++tt) {                                       \
        const int p = (kh * 3) * 256 + (es * 2 + tt) * 64 + lane;          \
        const s8 bh = *(const s8*)&bs[BUF][(p      ) * 8];                 \
        const s8 bm = *(const s8*)&bs[BUF][(p + 256) * 8];                 \
        const s8 bl = *(const s8*)&bs[BUF][(p + 512) * 8];                 \
        _Pragma("unroll")                                                  \
        for (int mt = 0; mt < 2; ++mt) {                                   \
            acc0[mt][tt] = MF(ah[mt],  bh, acc0[mt][tt]);                  \
            acc1[mt][tt] = MF(ah[mt],  bm, acc1[mt][tt]);                  \
            acc1[mt][tt] = MF(am_[mt], bh, acc1[mt][tt]);                  \
            acc1[mt][tt] = MF(ah[mt],  bl, acc1[mt][tt]);                  \
            acc1[mt][tt] = MF(am_[mt], bm, acc1[mt][tt]);                  \
            acc1[mt][tt] = MF(al[mt],  bh, acc1[mt][tt]);                  \
        }                                                                  \
    } }

    // prologue: chunk 0 in flight
    STAGE(0, 0);

    #pragma unroll
    for (int c = 0; c < 16; ++c) {
        __syncthreads();                 // publishes buf[c&1] (drains DMA)
        if (c + 1 < 16) STAGE((c + 1) & 1, c + 1);   // next chunk in flight
        COMPUTE(c & 1);
    }

    // K-half partials -> LDS (overlay dead B buffer 0: 17.4 KB < 24 KB).
    // bs[0] last cross-wave read was compute(14), ordered by the c=15
    // barrier -> safe to overwrite without an extra barrier.
    float (*Lsum)[32][68] = reinterpret_cast<float(*)[32][68]>(&bs[0][0]);
    #pragma unroll
    for (int mt = 0; mt < 2; ++mt)
        #pragma unroll
        for (int tt = 0; tt < 2; ++tt)
            #pragma unroll
            for (int r = 0; r < 4; ++r)
                Lsum[kh][mt * 16 + q * 4 + r][(es * 2 + tt) * 16 + m]
                    = acc0[mt][tt][r] + acc1[mt][tt][r];
    __syncthreads();

    // wave wv handles tokens wv*8 .. wv*8+7; lane = expert (r3-verified)
    #pragma unroll
    for (int tt = 0; tt < 8; ++tt) {
        const int tok  = wv * 8 + tt;
        const int gtok = tokBase + tok;
        const float ln = fmaf(nz[tt], nw,
                              Lsum[0][tok][lane] + Lsum[1][tok][lane]);

        float v1 = ln; int i1 = lane;
        #pragma unroll
        for (int off = 32; off > 0; off >>= 1) {
            const float vo = __shfl_xor(v1, off, 64);
            const int   io = __shfl_xor(i1, off, 64);
            if (vo > v1 || (vo == v1 && io < i1)) { v1 = vo; i1 = io; }
        }
        float v2 = (lane == i1) ? -3.4e38f : ln; int i2 = lane;
        #pragma unroll
        for (int off = 32; off > 0; off >>= 1) {
            const float vo = __shfl_xor(v2, off, 64);
            const int   io = __shfl_xor(i2, off, 64);
            if (vo > v2 || (vo == v2 && io < i2)) { v2 = vo; i2 = io; }
        }

        const float d   = expf(v2 - v1);
        const float inv = 1.f / (1.f + d);
        const float wgt = (lane == i1) ? inv : ((lane == i2) ? d * inv : 0.f);
        out_w[(size_t)gtok * NEXP + lane] = wgt;
        if (lane == 0) {
            out_i[(size_t)gtok * 2]     = (float)i1;
            out_i[(size_t)gtok * 2 + 1] = (float)i2;
        }
    }
}

extern "C" void kernel_launch(void* const* d_in, const int* in_sizes, int n_in,
                              void* d_out, int out_size, void* d_ws, size_t ws_size,
                              hipStream_t stream) {
    const float* x     = (const float*)d_in[0];
    const float* gw    = (const float*)d_in[1];
    const float* nwt   = (const float*)d_in[2];
    const float* noise = (const float*)d_in[3];
    float* out_w = (float*)d_out;                        // [NTOK][64]
    float* out_i = (float*)d_out + (size_t)NTOK * NEXP;  // [NTOK][2] as float

    short* wimg = (short*)d_ws;                          // 384 KB image

    hipLaunchKernelGGL(w_prep, dim3(32), dim3(256), 0, stream, gw, wimg);
    hipLaunchKernelGGL(gate_fused, dim3(NTOK / 32), dim3(256), 0, stream,
                       x, wimg, nwt, noise, out_w, out_i);
}

// Round 8
// 123.599 us; speedup vs baseline: 1.1242x; 1.0180x over previous
//
#include <hip/hip_runtime.h>
#include <math.h>

// TopKMoEGate: T = 16384, D = 1024, E = 64, topK = 2.
// Round 13: resubmit R12 (container infra failure, no kernel verdict).
//  - Ledger re-audited: prologue [nz(9), B0(6), x0(2), x1(2)]; iter c
//    issues [B_{c+1}(6), x_{c+2}(2)]. Outstanding at iter-c wait:
//    [x_c(2), B_c(6), x_{c+1}(2)] -> vmcnt(2) retires B_c + older.
//    c=15 -> vmcnt(0). Raw s_barrier cannot deadlock (uniform path).
//  - R11 post-mortem stands: __syncthreads' vmcnt(0) drain exposed
//    ~500cy HBM latency per chunk (x-stream) -> 48us. Counted vmcnt
//    (T4, m201-proven) keeps 10 DMA ops in flight across barriers.
//  - x ring-3 (24 KB) + B ring-2 (48 KB) = 72 KB -> 2 blocks/CU.
//  - Geometry/swizzle/numerics identical to R11 (verified, absmax
//    0.00390625): 512 blocks x 4 waves (es,kh), 32 tok, full E, full K.

#define DDIM 1024
#define NEXP 64
#define NTOK 16384

typedef float f4 __attribute__((ext_vector_type(4)));
typedef short s8 __attribute__((ext_vector_type(8)));
typedef unsigned int u32;

static __device__ __forceinline__ void split3(float f, short& h, short& m, short& l) {
    const u32 uf = __float_as_uint(f);
    h = (short)(uf >> 16);
    const float r1 = f - __uint_as_float(uf & 0xffff0000u);
    const u32 u1 = __float_as_uint(r1);
    m = (short)(u1 >> 16);
    const float r2 = r1 - __uint_as_float(u1 & 0xffff0000u);
    l = (short)(__float_as_uint(r2) >> 16);
}

static __device__ __forceinline__ void gl_lds16(const void* g, void* l) {
    __builtin_amdgcn_global_load_lds(
        (const __attribute__((address_space(1))) u32*)g,
        (__attribute__((address_space(3))) u32*)l, 16, 0, 0);
}

// ---- kernel 0: slice gate_w into 3 bf16 levels, lane-ordered image ----
// unit16 U'(c,kk,lv,t,q,m) = c*1536 + (kk*3+lv)*256 + t*64 + q*16 + m,
// holding w[e=t*16+m][k0..k0+7], k0 = c*64 + kk*32 + q*8.  24 KB per chunk.
__global__ __launch_bounds__(256)
void w_prep(const float* __restrict__ gw, short* __restrict__ wimg) {
    const int uid = blockIdx.x * 256 + threadIdx.x;   // 8192 threads
    const int c   = uid >> 9;
    const int kk  = (uid >> 8) & 1;
    const int e   = (uid >> 2) & 63;
    const int q   = uid & 3;
    const int k0  = c * 64 + kk * 32 + q * 8;
    const float* src = gw + (size_t)e * DDIM + k0;
    s8 hv, mv, lv;
    #pragma unroll
    for (int j = 0; j < 8; ++j) {
        short h, m, l;
        split3(src[j], h, m, l);
        hv[j] = h; mv[j] = m; lv[j] = l;
    }
    const size_t base = (size_t)c * 1536 + (kk * 3) * 256
                      + (e >> 4) * 64 + q * 16 + (e & 15);
    *(s8*)(wimg + (base      ) * 8) = hv;
    *(s8*)(wimg + (base + 256) * 8) = mv;
    *(s8*)(wimg + (base + 512) * 8) = lv;
}

// pack hi 16 bits of (flo, fhi) -> u32 {lo16 = hi(flo), hi16 = hi(fhi)}
static __device__ __forceinline__ u32 packhi(float flo, float fhi) {
    return __builtin_amdgcn_perm(__float_as_uint(fhi), __float_as_uint(flo),
                                 0x07060302u);
}

union FragU { u32 u[4]; s8 v; };

// convert 8 consecutive floats -> 3-level bf16 frags (h, m, l)  [r8-verified]
static __device__ __forceinline__ void conv8(const float* f, s8& h, s8& m, s8& l) {
    FragU H, M, L;
    #pragma unroll
    for (int j = 0; j < 4; ++j) {
        const float f0 = f[2 * j], f1 = f[2 * j + 1];
        H.u[j] = packhi(f0, f1);
        const float g0 = f0 - __uint_as_float(__float_as_uint(f0) & 0xffff0000u);
        const float g1 = f1 - __uint_as_float(__float_as_uint(f1) & 0xffff0000u);
        M.u[j] = packhi(g0, g1);
        const float e0 = g0 - __uint_as_float(__float_as_uint(g0) & 0xffff0000u);
        const float e1 = g1 - __uint_as_float(__float_as_uint(g1) & 0xffff0000u);
        L.u[j] = packhi(e0, e1);
    }
    h = H.v; m = M.v; l = L.v;
}

#define MF(A, B, C) __builtin_amdgcn_mfma_f32_16x16x32_bf16((A), (B), (C), 0, 0, 0)

// ---- kernel 1: fused GEMM + noisy top-2 + sparse softmax ----
__global__ __launch_bounds__(256, 2)
void gate_fused(const float* __restrict__ x,
                const short* __restrict__ wimg,
                const float* __restrict__ noise_weight,
                const float* __restrict__ noise,
                float* __restrict__ out_w,
                float* __restrict__ out_i)
{
    __shared__ short bs[2][1536 * 8];           // B ring-2: 2 x 24 KB
    __shared__ float xs[3][32 * 64];            // x ring-3: 3 x 8 KB (swizzled)

    const int tid  = threadIdx.x;
    const int lane = tid & 63;
    const int wv   = tid >> 6;
    const int es   = wv & 1;                    // expert half (2 t-tiles)
    const int kh   = wv >> 1;                   // k32 half of each chunk
    const int m    = lane & 15;
    const int q    = lane >> 4;
    const int tokBase = blockIdx.x * 32;

    // epilogue operands FIRST (oldest in vmcnt order; retire under wait 0)
    const float nw = noise_weight[lane];
    float nz[8];
    #pragma unroll
    for (int tt = 0; tt < 8; ++tt)
        nz[tt] = noise[(size_t)(tokBase + wv * 8 + tt) * NEXP + lane];

    f4 acc0[2][2], acc1[2][2];                  // [mt][tt]
    #pragma unroll
    for (int a = 0; a < 2; ++a)
        #pragma unroll
        for (int b = 0; b < 2; ++b) { acc0[a][b] = (f4)0.f; acc1[a][b] = (f4)0.f; }

#define STAGE_B(BUF, C) {                                                  \
    const short* _c = wimg + (size_t)(C) * 12288;                          \
    _Pragma("unroll")                                                      \
    for (int _i = 0; _i < 6; ++_i) {                                       \
        const int _off = (wv * 6 + _i) * 512;                              \
        gl_lds16(_c + _off + lane * 8, &bs[BUF][_off]);                    \
    } }

#define STAGE_X(BUF, C) {                                                  \
    _Pragma("unroll")                                                      \
    for (int _j = 0; _j < 2; ++_j) {                                       \
        const int _qi = (wv * 2 + _j) * 64 + lane;                         \
        const int _tk = _qi >> 4;                                          \
        const int _qd = (_qi & 15) ^ (_tk & 15);                           \
        gl_lds16(x + (size_t)(tokBase + _tk) * DDIM + (C) * 64 + _qd * 4,  \
                 &xs[BUF][(wv * 2 + _j) * 256]);                           \
    } }

    // consume chunk from bs[BUF], xs[XBUF]: wave (es,kh), 2 mt x 2 tt x 6 MFMA
#define COMPUTE(BUF, XBUF) {                                               \
    s8 ah[2], am_[2], al[2];                                               \
    _Pragma("unroll")                                                      \
    for (int mt = 0; mt < 2; ++mt) {                                       \
        const int tok = mt * 16 + m;                                       \
        const int qd0 = kh * 8 + q * 2;                                    \
        const int sq0 = qd0 ^ (tok & 15);                                  \
        const int sq1 = (qd0 + 1) ^ (tok & 15);                            \
        const f4 xa = *(const f4*)&xs[XBUF][tok * 64 + sq0 * 4];           \
        const f4 xb = *(const f4*)&xs[XBUF][tok * 64 + sq1 * 4];           \
        float xf[8];                                                       \
        _Pragma("unroll")                                                  \
        for (int i = 0; i < 4; ++i) { xf[i] = xa[i]; xf[4 + i] = xb[i]; }  \
        conv8(xf, ah[mt], am_[mt], al[mt]);                                \
    }                                                                      \
    _Pragma("unroll")                                                      \
    for (int tt = 0; tt < 2; ++tt) {                                       \
        const int p = (kh * 3) * 256 + (es * 2 + tt) * 64 + lane;          \
        const s8 bh = *(const s8*)&bs[BUF][(p      ) * 8];                 \
        const s8 bm = *(const s8*)&bs[BUF][(p + 256) * 8];                 \
        const s8 bl = *(const s8*)&bs[BUF][(p + 512) * 8];                 \
        _Pragma("unroll")                                                  \
        for (int mt = 0; mt < 2; ++mt) {                                   \
            acc0[mt][tt] = MF(ah[mt],  bh, acc0[mt][tt]);                  \
            acc1[mt][tt] = MF(ah[mt],  bm, acc1[mt][tt]);                  \
            acc1[mt][tt] = MF(am_[mt], bh, acc1[mt][tt]);                  \
            acc1[mt][tt] = MF(ah[mt],  bl, acc1[mt][tt]);                  \
            acc1[mt][tt] = MF(am_[mt], bm, acc1[mt][tt]);                  \
            acc1[mt][tt] = MF(al[mt],  bh, acc1[mt][tt]);                  \
        }                                                                  \
    } }

    // prologue issue order: nz(9) | B0(6) | x0(2) | x1(2)
    STAGE_B(0, 0);
    STAGE_X(0, 0);
    STAGE_X(1, 1);

    #pragma unroll
    for (int c = 0; c < 16; ++c) {
        // chunk c needs B_c (x_c is older in issue order).  After B_c the
        // only younger op is x_{c+1} (2) -> N=2; at c=15 nothing -> N=0.
        if (c < 15) {
            asm volatile("s_waitcnt vmcnt(2)" ::: "memory");
        } else {
            asm volatile("s_waitcnt vmcnt(0) lgkmcnt(0)" ::: "memory");
        }
        __builtin_amdgcn_sched_barrier(0);
        __builtin_amdgcn_s_barrier();           // raw: NO vmcnt(0) drain
        if (c + 1 < 16) STAGE_B((c + 1) & 1, c + 1);
        if (c + 2 < 16) STAGE_X((c + 2) % 3, c + 2);
        __builtin_amdgcn_sched_barrier(0);      // pin stage before compute
        COMPUTE(c & 1, c % 3);
    }

    // K-half partials -> LDS (overlay dead B buffer 0; chunk 15 used buf 1,
    // bs[0]'s last reader finished before the c=15 barrier).
    float (*Lsum)[32][68] = reinterpret_cast<float(*)[32][68]>(&bs[0][0]);
    #pragma unroll
    for (int mt = 0; mt < 2; ++mt)
        #pragma unroll
        for (int tt = 0; tt < 2; ++tt)
            #pragma unroll
            for (int r = 0; r < 4; ++r)
                Lsum[kh][mt * 16 + q * 4 + r][(es * 2 + tt) * 16 + m]
                    = acc0[mt][tt][r] + acc1[mt][tt][r];
    __syncthreads();

    // wave wv handles tokens wv*8 .. wv*8+7; lane = expert (r3-verified)
    #pragma unroll
    for (int tt = 0; tt < 8; ++tt) {
        const int tok  = wv * 8 + tt;
        const int gtok = tokBase + tok;
        const float ln = fmaf(nz[tt], nw,
                              Lsum[0][tok][lane] + Lsum[1][tok][lane]);

        float v1 = ln; int i1 = lane;
        #pragma unroll
        for (int off = 32; off > 0; off >>= 1) {
            const float vo = __shfl_xor(v1, off, 64);
            const int   io = __shfl_xor(i1, off, 64);
            if (vo > v1 || (vo == v1 && io < i1)) { v1 = vo; i1 = io; }
        }
        float v2 = (lane == i1) ? -3.4e38f : ln; int i2 = lane;
        #pragma unroll
        for (int off = 32; off > 0; off >>= 1) {
            const float vo = __shfl_xor(v2, off, 64);
            const int   io = __shfl_xor(i2, off, 64);
            if (vo > v2 || (vo == v2 && io < i2)) { v2 = vo; i2 = io; }
        }

        const float d   = expf(v2 - v1);
        const float inv = 1.f / (1.f + d);
        const float wgt = (lane == i1) ? inv : ((lane == i2) ? d * inv : 0.f);
        out_w[(size_t)gtok * NEXP + lane] = wgt;
        if (lane == 0) {
            out_i[(size_t)gtok * 2]     = (float)i1;
            out_i[(size_t)gtok * 2 + 1] = (float)i2;
        }
    }
}

extern "C" void kernel_launch(void* const* d_in, const int* in_sizes, int n_in,
                              void* d_out, int out_size, void* d_ws, size_t ws_size,
                              hipStream_t stream) {
    const float* x     = (const float*)d_in[0];
    const float* gw    = (const float*)d_in[1];
    const float* nwt   = (const float*)d_in[2];
    const float* noise = (const float*)d_in[3];
    float* out_w = (float*)d_out;                        // [NTOK][64]
    float* out_i = (float*)d_out + (size_t)NTOK * NEXP;  // [NTOK][2] as float

    short* wimg = (short*)d_ws;                          // 384 KB image

    hipLaunchKernelGGL(w_prep, dim3(32), dim3(256), 0, stream, gw, wimg);
    hipLaunchKernelGGL(gate_fused, dim3(NTOK / 32), dim3(256), 0, stream,
                       x, wimg, nwt, noise, out_w, out_i);
}